// Round 5
// baseline (420.978 us; speedup 1.0000x reference)
//
#include <hip/hip_runtime.h>
#include <cstddef>
#include <cstdint>

// x (32,64,64,16) f32; W (16,16,448,448) f32; bias (16,16) f32.
// Kept bands per axis: {cA6, cD6, cD5, cD1} -> full-layout band blocks {0,1,2,6}.
// X1 (reused in place as Z1): (a, u in [0,256), j in [0,64), ch 16) = 32 MB in d_ws.

#define X1_IDX(a,u,j,d) ((((size_t)(a)*256 + (u))*64 + (j))*16 + (d))

// ---------------- K1: SWT along axis 1 (i -> u bands), x -> X1 ----------------
// block 256 = q(4 i-quarters) x jl(4) x d(16); grid (32 a, 16 jc). 8 waves/CU.
__global__ __launch_bounds__(256, 2) void k_swt1(const float* __restrict__ x,
                                                 float* __restrict__ X1) {
  __shared__ float col[64 * 64];  // [i][c], c = jl*16+d
  __shared__ float Ps[4][64];
  const int t = threadIdx.x;
  const int q = t >> 6, c = t & 63, jl = c >> 4, d = c & 15;
  const int a = blockIdx.x, j = blockIdx.y * 4 + jl;
  const float* xp = x + ((size_t)a * 4096 + j) * 16 + d + (size_t)(q * 16) * 1024;
  float P = 0.f;
#pragma unroll
  for (int r = 0; r < 16; ++r) {
    float v = xp[(size_t)r * 1024];
    col[(q * 16 + r) * 64 + c] = v;
    P += v;
  }
  Ps[q][c] = P;
  __syncthreads();
  const float cA = (Ps[0][c] + Ps[1][c] + Ps[2][c] + Ps[3][c]) * 0.015625f;
  float w4 = Ps[q][c], w4b = Ps[(q + 1) & 3][c];
  float w5 = w4 + w4b;
  float* X1p = X1 + X1_IDX(a, 0, j, d);  // stride per u = 1024
#pragma unroll
  for (int r = 0; r < 16; ++r) {
    const int u = q * 16 + r;
    const float c0 = col[u * 64 + c];
    const float c1 = col[((u + 1) & 63) * 64 + c];
    const float c16 = col[((u + 16) & 63) * 64 + c];
    const float c32 = col[((u + 32) & 63) * 64 + c];
    X1p[(size_t)(u) * 1024]       = cA;
    X1p[(size_t)(64 + u) * 1024]  = w5 * 0.03125f - cA;
    X1p[(size_t)(128 + u) * 1024] = (w4 - w4b) * 0.03125f;
    X1p[(size_t)(192 + u) * 1024] = (c0 - c1) * 0.5f;
    w4 += c16 - c0;
    w4b += c32 - c16;
    w5 += c32 - c0;
  }
}

// ---------------- Fused: axis-2 SWT -> channel mix -> axis-2 iSWT ----------------
// APB=2, Ts v-stride 20 (16B aligned, <=2-way banks), Wl stride-18 double buffer.
// LDS = 40960 + 36864 + 1024 = 78.8 KB -> 2 blocks/CU (8 waves/CU).
// bid -> (u, ac): u = (bid&7) + 8*(bid>>7)  => all 16 same-u blocks on one XCD,
// temporally adjacent -> W panel read once per u.
#define TSS 20
#define TSA (256 * TSS)
#define TS2(a,v,d) ((a) * TSA + (v) * TSS + (d))
#define WLS 18

__global__ __launch_bounds__(256, 2) void k_fused(float* __restrict__ X1,
                                                  const float* __restrict__ W) {
  __shared__ float Ts[2 * TSA];         // 40,960 B
  __shared__ float Wl[2 * 256 * WLS];   // 36,864 B
  __shared__ float Ps[2 * 8 * 16];      //  1,024 B
  const int t = threadIdx.x;
  const int bid = blockIdx.x;
  const int u = (bid & 7) + 8 * (bid >> 7);
  const int ac = (bid >> 3) & 15;
  const int a0 = ac * 2;
  const int ub = u >> 6;
  const int Brow = (ub == 3 ? 6 : ub) * 64 + (u & 63);

  const int aA = t >> 7, qA = (t >> 4) & 7, dA = t & 15;

  // ---- Phase A: stage raw column into band-3 area; compute bands ----
  {
    const float* xp = X1 + X1_IDX(a0 + aA, u, qA * 8, dA);
    float P = 0.f;
#pragma unroll
    for (int r = 0; r < 8; ++r) {
      float v = xp[r * 16];
      Ts[TS2(aA, 192 + qA * 8 + r, dA)] = v;  // staging
      P += v;
    }
    Ps[aA * 128 + qA * 16 + dA] = P;
  }
  __syncthreads();
  {
    float cA = 0.f;
#pragma unroll
    for (int k = 0; k < 8; ++k) cA += Ps[aA * 128 + k * 16 + dA];
    cA *= 0.015625f;
    float w4 = Ps[aA * 128 + qA * 16 + dA] + Ps[aA * 128 + (((qA + 1) & 7) * 16) + dA];
    float w4b = Ps[aA * 128 + (((qA + 2) & 7) * 16) + dA] + Ps[aA * 128 + (((qA + 3) & 7) * 16) + dA];
    float w5 = w4 + w4b;
    float cd1[8];
#pragma unroll
    for (int r = 0; r < 8; ++r) {
      const int v = qA * 8 + r;
      const float c0 = Ts[TS2(aA, 192 + v, dA)];
      const float c1 = Ts[TS2(aA, 192 + ((v + 1) & 63), dA)];
      const float c16 = Ts[TS2(aA, 192 + ((v + 16) & 63), dA)];
      const float c32 = Ts[TS2(aA, 192 + ((v + 32) & 63), dA)];
      Ts[TS2(aA, v, dA)]       = cA;
      Ts[TS2(aA, 64 + v, dA)]  = w5 * 0.03125f - cA;
      Ts[TS2(aA, 128 + v, dA)] = (w4 - w4b) * 0.03125f;
      cd1[r] = (c0 - c1) * 0.5f;
      w4 += c16 - c0;
      w4b += c32 - c16;
      w5 += c32 - c0;
    }
    __syncthreads();
#pragma unroll
    for (int r = 0; r < 8; ++r) Ts[TS2(aA, 192 + qA * 8 + r, dA)] = cd1[r];
  }
  __syncthreads();

  // ---- Phase B: channel mix in place, W double-buffered one vg ahead ----
  const int vl = t >> 4, e = t & 15;
  const float* wbase = W + (size_t)t * 200704 + (size_t)Brow * 448;
  float4 pw0, pw1, pw2, pw3;
  {
    const float* wp = wbase;  // Ccol(vg=0) = 0
    pw0 = *(const float4*)(wp + 0);
    pw1 = *(const float4*)(wp + 4);
    pw2 = *(const float4*)(wp + 8);
    pw3 = *(const float4*)(wp + 12);
  }
  for (int vg = 0; vg < 16; ++vg) {
    const int buf = vg & 1;
    {
      float* wrow = &Wl[(buf * 256 + t) * WLS];
      *(float2*)&wrow[0]  = make_float2(pw0.x, pw0.y);
      *(float2*)&wrow[2]  = make_float2(pw0.z, pw0.w);
      *(float2*)&wrow[4]  = make_float2(pw1.x, pw1.y);
      *(float2*)&wrow[6]  = make_float2(pw1.z, pw1.w);
      *(float2*)&wrow[8]  = make_float2(pw2.x, pw2.y);
      *(float2*)&wrow[10] = make_float2(pw2.z, pw2.w);
      *(float2*)&wrow[12] = make_float2(pw3.x, pw3.y);
      *(float2*)&wrow[14] = make_float2(pw3.z, pw3.w);
    }
    __syncthreads();
    if (vg < 15) {
      const int v2 = vg + 1;
      const int kb2 = v2 >> 2;
      const float* wp = wbase + (kb2 == 3 ? 384 : kb2 * 64) + (v2 & 3) * 16;
      pw0 = *(const float4*)(wp + 0);
      pw1 = *(const float4*)(wp + 4);
      pw2 = *(const float4*)(wp + 8);
      pw3 = *(const float4*)(wp + 12);
    }
    float wreg[16];
#pragma unroll
    for (int d = 0; d < 16; ++d)
      wreg[d] = Wl[(buf * 256 + d * 16 + e) * WLS + vl];
    const int v = vg * 16 + vl;
#pragma unroll
    for (int a = 0; a < 2; ++a) {
      const float4 t0 = *(const float4*)&Ts[TS2(a, v, 0)];
      const float4 t1 = *(const float4*)&Ts[TS2(a, v, 4)];
      const float4 t2 = *(const float4*)&Ts[TS2(a, v, 8)];
      const float4 t3 = *(const float4*)&Ts[TS2(a, v, 12)];
      float acc = t0.x * wreg[0] + t0.y * wreg[1] + t0.z * wreg[2] + t0.w * wreg[3]
                + t1.x * wreg[4] + t1.y * wreg[5] + t1.z * wreg[6] + t1.w * wreg[7]
                + t2.x * wreg[8] + t2.y * wreg[9] + t2.z * wreg[10] + t2.w * wreg[11]
                + t3.x * wreg[12] + t3.y * wreg[13] + t3.z * wreg[14] + t3.w * wreg[15];
      // all 16 readers of (a,v) are lanes of this wave; DS in-order -> safe in-place
      Ts[TS2(a, v, e)] = acc;
    }
  }
  __syncthreads();

  // ---- Phase C: axis-2 iSWT via LDS ping-pong over band areas ----
  // thread = (aC, qC 8 x 8 i's, eC)
  {
    const int aC = t >> 7, qC = (t >> 4) & 7, eC = t & 15;
    float rg[8];
    // L6: b6[i] = 0.5*(y0[i]+y1[i]+y0[i-32]-y1[i-32]) -> band0
#pragma unroll
    for (int r = 0; r < 8; ++r) {
      const int i = qC * 8 + r, i2 = (i - 32) & 63;
      rg[r] = 0.5f * (Ts[TS2(aC, i, eC)] + Ts[TS2(aC, 64 + i, eC)]
                    + Ts[TS2(aC, i2, eC)] - Ts[TS2(aC, 64 + i2, eC)]);
    }
    __syncthreads();
#pragma unroll
    for (int r = 0; r < 8; ++r) Ts[TS2(aC, qC * 8 + r, eC)] = rg[r];
    __syncthreads();
    // L5: a5[i] = 0.5*(b6[i]+d5[i]+b6[i-16]-d5[i-16]) -> band1
#pragma unroll
    for (int r = 0; r < 8; ++r) {
      const int i = qC * 8 + r, i2 = (i - 16) & 63;
      rg[r] = 0.5f * (Ts[TS2(aC, i, eC)] + Ts[TS2(aC, 128 + i, eC)]
                    + Ts[TS2(aC, i2, eC)] - Ts[TS2(aC, 128 + i2, eC)]);
    }
    __syncthreads();
#pragma unroll
    for (int r = 0; r < 8; ++r) Ts[TS2(aC, 64 + qC * 8 + r, eC)] = rg[r];
    __syncthreads();
    // L4*L3*L2 composed: b2[i] = (1/8) sum_{k=0}^{7} a5[(i-2k)&63] -> band0
#pragma unroll
    for (int r = 0; r < 8; ++r) {
      const int i = qC * 8 + r;
      float s = 0.f;
#pragma unroll
      for (int k = 0; k < 8; ++k) s += Ts[TS2(aC, 64 + ((i - 2 * k) & 63), eC)];
      rg[r] = s * 0.125f;
    }
    __syncthreads();
#pragma unroll
    for (int r = 0; r < 8; ++r) Ts[TS2(aC, qC * 8 + r, eC)] = rg[r];
    __syncthreads();
    // L1: out = 0.5*(b2[i]+d1[i]+b2[i-1]-d1[i-1]) -> global (in place over X1)
    float* zp = X1 + X1_IDX(a0 + aC, u, 0, eC);
#pragma unroll
    for (int r = 0; r < 8; ++r) {
      const int i = qC * 8 + r, i2 = (i - 1) & 63;
      zp[i * 16] = 0.5f * (Ts[TS2(aC, i, eC)] + Ts[TS2(aC, 192 + i, eC)]
                         + Ts[TS2(aC, i2, eC)] - Ts[TS2(aC, 192 + i2, eC)]);
    }
  }
}

// ---------------- K5: axis-1 iSWT + bias skip -> out ----------------
// block 256 = q(4) x jl(4) x e(16); grid (32 a, 16 jc). LDS ping-pong, bias in regs.
__global__ __launch_bounds__(256, 2) void k_iswt1(const float* __restrict__ Z1,
                                                  const float* __restrict__ x,
                                                  const float* __restrict__ bias,
                                                  float* __restrict__ out) {
  __shared__ float A[64 * 64], Bb[64 * 64], D[64 * 64], xs[64 * 64];  // 64 KB
  const int t = threadIdx.x;
  const int q = t >> 6, c = t & 63, jl = c >> 4, e = c & 15;
  const int a = blockIdx.x, j = blockIdx.y * 4 + jl;
  // bias row for this thread's e in registers
  float breg[16];
  {
    const float4 b0 = *(const float4*)&bias[e * 16 + 0];
    const float4 b1 = *(const float4*)&bias[e * 16 + 4];
    const float4 b2 = *(const float4*)&bias[e * 16 + 8];
    const float4 b3 = *(const float4*)&bias[e * 16 + 12];
    breg[0]=b0.x; breg[1]=b0.y; breg[2]=b0.z; breg[3]=b0.w;
    breg[4]=b1.x; breg[5]=b1.y; breg[6]=b1.z; breg[7]=b1.w;
    breg[8]=b2.x; breg[9]=b2.y; breg[10]=b2.z; breg[11]=b2.w;
    breg[12]=b3.x; breg[13]=b3.y; breg[14]=b3.z; breg[15]=b3.w;
  }
  const float* Zp = Z1 + (size_t)a * 262144 + (size_t)j * 16 + e;  // + u*1024
  // stage band0 -> A, band1 -> D, and x (d=e slice) -> xs
#pragma unroll
  for (int r = 0; r < 16; ++r) {
    const int i = q * 16 + r;
    A[i * 64 + c] = Zp[(size_t)i * 1024];
    D[i * 64 + c] = Zp[(size_t)(64 + i) * 1024];
    xs[i * 64 + c] = x[((size_t)a * 4096 + (size_t)i * 64 + j) * 16 + e];
  }
  __syncthreads();
  float rg[16];
  // L6 -> Bb ; stage cD5 -> D
#pragma unroll
  for (int r = 0; r < 16; ++r) {
    const int i = q * 16 + r, i2 = (i - 32) & 63;
    rg[r] = 0.5f * (A[i * 64 + c] + D[i * 64 + c] + A[i2 * 64 + c] - D[i2 * 64 + c]);
  }
  __syncthreads();
#pragma unroll
  for (int r = 0; r < 16; ++r) {
    const int i = q * 16 + r;
    Bb[i * 64 + c] = rg[r];
    D[i * 64 + c] = Zp[(size_t)(128 + i) * 1024];
  }
  __syncthreads();
  // L5 -> A ; stage cD1 -> D
#pragma unroll
  for (int r = 0; r < 16; ++r) {
    const int i = q * 16 + r, i2 = (i - 16) & 63;
    rg[r] = 0.5f * (Bb[i * 64 + c] + D[i * 64 + c] + Bb[i2 * 64 + c] - D[i2 * 64 + c]);
  }
  __syncthreads();
#pragma unroll
  for (int r = 0; r < 16; ++r) {
    const int i = q * 16 + r;
    A[i * 64 + c] = rg[r];
    D[i * 64 + c] = Zp[(size_t)(192 + i) * 1024];
  }
  __syncthreads();
  // L4*L3*L2 composed -> Bb
#pragma unroll
  for (int r = 0; r < 16; ++r) {
    const int i = q * 16 + r;
    float s = 0.f;
#pragma unroll
    for (int k = 0; k < 8; ++k) s += A[((i - 2 * k) & 63) * 64 + c];
    rg[r] = s * 0.125f;
  }
  __syncthreads();
#pragma unroll
  for (int r = 0; r < 16; ++r) Bb[(q * 16 + r) * 64 + c] = rg[r];
  __syncthreads();
  // L1 + skip -> out
#pragma unroll
  for (int r = 0; r < 16; ++r) {
    const int i = q * 16 + r, i2 = (i - 1) & 63;
    float v = 0.5f * (Bb[i * 64 + c] + D[i * 64 + c] + Bb[i2 * 64 + c] - D[i2 * 64 + c]);
    float s = 0.f;
#pragma unroll
    for (int dd = 0; dd < 16; ++dd) s += xs[i * 64 + jl * 16 + dd] * breg[dd];
    out[((size_t)a * 4096 + (size_t)i * 64 + j) * 16 + e] = v + s;
  }
}

extern "C" void kernel_launch(void* const* d_in, const int* in_sizes, int n_in,
                              void* d_out, int out_size, void* d_ws, size_t ws_size,
                              hipStream_t stream) {
  const float* x = (const float*)d_in[0];
  const float* W = (const float*)d_in[1];
  const float* bias = (const float*)d_in[2];
  float* out = (float*)d_out;
  float* X1 = (float*)d_ws;  // 32 MB; both X1 and Z1 (fused stage is in place)

  k_swt1<<<dim3(32, 16), 256, 0, stream>>>(x, X1);
  k_fused<<<dim3(4096), 256, 0, stream>>>(X1, W);
  k_iswt1<<<dim3(32, 16), 256, 0, stream>>>(X1, x, bias, out);
}